// Round 1
// baseline (296.968 us; speedup 1.0000x reference)
//
#include <hip/hip_runtime.h>

typedef __bf16 bf16x8 __attribute__((ext_vector_type(8)));
typedef float f32x4 __attribute__((ext_vector_type(4)));

#define B_TOT   16384
#define DM      512
#define NF      64
#define KU      96   // padded K for final GEMM: 8 G + 64 P + 1 eye + 23 zero

#define MFMA16(a,b,c) __builtin_amdgcn_mfma_f32_16x16x32_bf16(a,b,c,0,0,0)

static __device__ __forceinline__ bf16x8 load_cvt8(const float* __restrict__ p) {
  float4 a = *(const float4*)p;
  float4 b = *(const float4*)(p + 4);
  bf16x8 r;
  r[0]=(__bf16)a.x; r[1]=(__bf16)a.y; r[2]=(__bf16)a.z; r[3]=(__bf16)a.w;
  r[4]=(__bf16)b.x; r[5]=(__bf16)b.y; r[6]=(__bf16)b.z; r[7]=(__bf16)b.w;
  return r;
}

// K0: convert W1 (512x512 f32, row-major [n][k]) to bf16
__global__ __launch_bounds__(256) void cvt_w1_kernel(const float* __restrict__ W1,
                                                     __bf16* __restrict__ W1b) {
  int idx = blockIdx.x * 256 + threadIdx.x;  // grid 1024 -> exactly 262144
  W1b[idx] = (__bf16)W1[idx];
}

// K2: build Vt[4096][96] bf16: cols 0..7 = G_r[ij], 8..71 = (G_r G_s)[ij],
// 72 = eye[ij], 73..95 = 0
__global__ __launch_bounds__(256) void build_vt_kernel(const float* __restrict__ gen,
                                                       __bf16* __restrict__ Vt) {
  const int tid = threadIdx.x;
  const int bid = blockIdx.x;
  if (bid < 64) {
    __shared__ float Ga[NF*NF];
    __shared__ float Gb[NF*NF];
    const int r = bid >> 3, s = bid & 7;
    for (int i = tid; i < NF*NF; i += 256) {
      Ga[i] = gen[r*NF*NF + i];
      Gb[i] = gen[s*NF*NF + i];
    }
    __syncthreads();
    const int i  = tid >> 2;          // 0..63
    const int j0 = (tid & 3) * 16;    // 0,16,32,48
    float acc[16];
    #pragma unroll
    for (int jj = 0; jj < 16; ++jj) acc[jj] = 0.f;
    for (int k = 0; k < NF; ++k) {
      float a = Ga[i*NF + k];
      #pragma unroll
      for (int jj = 0; jj < 16; ++jj) acc[jj] += a * Gb[k*NF + j0 + jj];
    }
    #pragma unroll
    for (int jj = 0; jj < 16; ++jj)
      Vt[(size_t)(i*NF + j0 + jj)*KU + 8 + bid] = (__bf16)acc[jj];
  } else {
    for (int idx = tid; idx < NF*NF; idx += 256) {
      #pragma unroll
      for (int r = 0; r < 8; ++r) Vt[(size_t)idx*KU + r] = (__bf16)gen[r*NF*NF + idx];
      const int i = idx >> 6, j = idx & 63;
      Vt[(size_t)idx*KU + 72] = (__bf16)((i == j) ? 1.f : 0.f);
      #pragma unroll
      for (int k = 73; k < KU; ++k) Vt[(size_t)idx*KU + k] = (__bf16)0.f;
    }
  }
}

// K1: fused  Gs=x_s@W1^T, Ge=x_e@W1^T  (bf16 MFMA, fp32 accum)
//  -> per step: h=gelu((1-t)Gs + t Ge + b1); z_r = h.W2_r; c=tanh(z+b2)*scale
//  -> csum_r = dt*sum_i c_i,r ;  u[b] = [c_r, 0.5 c_r c_s, 1, 0...]
// One WG (256 thr, 4 waves) per 16 batch rows; wave w owns cols [w*128, w*128+128)
__global__ __launch_bounds__(256) void coeff_kernel(
    const float* __restrict__ xs, const float* __restrict__ xe,
    const __bf16* __restrict__ W1b,
    const float* __restrict__ b1, const float* __restrict__ W2,
    const float* __restrict__ b2, const float* __restrict__ scale_p,
    __bf16* __restrict__ u) {
  const int tid = threadIdx.x;
  const int l  = tid & 63, w = tid >> 6;
  const int lc = l & 15,  lg = l >> 4;
  const int m0 = blockIdx.x * 16;

  __shared__ float W2s[8*DM];
  __shared__ float zs[4][16][8];
  __shared__ float cshr[16][8];

  for (int i = tid; i < 8*DM; i += 256) W2s[i] = W2[i];
  __syncthreads();

  f32x4 accS[8], accE[8];
  #pragma unroll
  for (int nt = 0; nt < 8; ++nt) { accS[nt] = (f32x4)0.f; accE[nt] = (f32x4)0.f; }

  const float*  xsp   = xs  + (size_t)(m0 + lc)*DM + lg*8;
  const float*  xep   = xe  + (size_t)(m0 + lc)*DM + lg*8;
  const __bf16* wbase = W1b + (size_t)(w*128 + lc)*DM + lg*8;

  for (int ks = 0; ks < 16; ++ks) {
    const int k0 = ks*32;
    bf16x8 aS = load_cvt8(xsp + k0);
    bf16x8 aE = load_cvt8(xep + k0);
    #pragma unroll
    for (int nt = 0; nt < 8; ++nt) {
      bf16x8 bF = *(const bf16x8*)(wbase + (size_t)nt*16*DM + k0);
      accS[nt] = MFMA16(aS, bF, accS[nt]);
      accE[nt] = MFMA16(aE, bF, accE[nt]);
    }
  }

  // per-lane constants for epilogue: W2 and b1 at this lane's 8 columns
  float w2l[8][8];  // [nt][r]
  float b1l[8];
  #pragma unroll
  for (int nt = 0; nt < 8; ++nt) {
    const int n = (w*8 + nt)*16 + lc;
    b1l[nt] = b1[n];
    #pragma unroll
    for (int r = 0; r < 8; ++r) w2l[nt][r] = W2s[r*DM + n];
  }
  const float scale = *scale_p;

  float csacc = 0.f;  // valid for tid<128: (m=tid>>3, r=tid&7)
  #pragma unroll
  for (int i = 0; i < 4; ++i) {
    const float t  = (i + 0.5f) * 0.25f;
    const float omt = 1.f - t;
    float pz[4][8];
    #pragma unroll
    for (int rg = 0; rg < 4; ++rg)
      #pragma unroll
      for (int r = 0; r < 8; ++r) pz[rg][r] = 0.f;

    #pragma unroll
    for (int nt = 0; nt < 8; ++nt) {
      #pragma unroll
      for (int rg = 0; rg < 4; ++rg) {
        float mid = omt*accS[nt][rg] + t*accE[nt][rg] + b1l[nt];
        float h = 0.5f * mid * (1.f + erff(mid * 0.70710678118f));
        #pragma unroll
        for (int r = 0; r < 8; ++r) pz[rg][r] += h * w2l[nt][r];
      }
    }
    // reduce over the 16 lanes (cols) of each lane-group
    #pragma unroll
    for (int rg = 0; rg < 4; ++rg)
      #pragma unroll
      for (int r = 0; r < 8; ++r) {
        float v = pz[rg][r];
        v += __shfl_xor(v, 1); v += __shfl_xor(v, 2);
        v += __shfl_xor(v, 4); v += __shfl_xor(v, 8);
        pz[rg][r] = v;
      }
    if (lc == 0) {
      #pragma unroll
      for (int rg = 0; rg < 4; ++rg)
        #pragma unroll
        for (int r = 0; r < 8; ++r) zs[w][lg*4 + rg][r] = pz[rg][r];
    }
    __syncthreads();
    if (tid < 128) {
      const int m = tid >> 3, r = tid & 7;
      float z = zs[0][m][r] + zs[1][m][r] + zs[2][m][r] + zs[3][m][r] + b2[r];
      csacc += tanhf(z);
    }
    __syncthreads();
  }

  if (tid < 128) cshr[tid >> 3][tid & 7] = csacc * 0.25f * scale;  // * dt * scale
  __syncthreads();

  for (int idx = tid; idx < 16*KU; idx += 256) {
    const int m = idx / KU, k = idx - m*KU;
    float val;
    if (k < 8)        val = cshr[m][k];
    else if (k < 72)  { const int rs = k - 8; val = 0.5f * cshr[m][rs >> 3] * cshr[m][rs & 7]; }
    else if (k == 72) val = 1.f;
    else              val = 0.f;
    u[(size_t)(m0 + m)*KU + k] = (__bf16)val;
  }
}

// K3: out[b][ij] = sum_k u[b][k] * Vt[ij][k]   (M=16384, N=4096, K=96)
// WG tile 64x64, 4 waves in 2x2, each wave 32x32 = 2x2 MFMA tiles
__global__ __launch_bounds__(256) void out_gemm_kernel(
    const __bf16* __restrict__ u, const __bf16* __restrict__ Vt,
    float* __restrict__ out) {
  const int bid = blockIdx.x;
  const int mb = bid >> 6, nb = bid & 63;
  const int tid = threadIdx.x;
  const int l  = tid & 63, w = tid >> 6;
  const int lc = l & 15,  lg = l >> 4;
  const int mw = w >> 1,  nw = w & 1;
  const int m0 = mb*64 + mw*32;
  const int n0 = nb*64 + nw*32;

  f32x4 acc[2][2];
  #pragma unroll
  for (int a = 0; a < 2; ++a)
    #pragma unroll
    for (int b = 0; b < 2; ++b) acc[a][b] = (f32x4)0.f;

  #pragma unroll
  for (int ks = 0; ks < 3; ++ks) {
    const int k0 = ks*32 + lg*8;
    bf16x8 aF[2], bF[2];
    #pragma unroll
    for (int a = 0; a < 2; ++a)
      aF[a] = *(const bf16x8*)(u + (size_t)(m0 + a*16 + lc)*KU + k0);
    #pragma unroll
    for (int b = 0; b < 2; ++b)
      bF[b] = *(const bf16x8*)(Vt + (size_t)(n0 + b*16 + lc)*KU + k0);
    #pragma unroll
    for (int a = 0; a < 2; ++a)
      #pragma unroll
      for (int b = 0; b < 2; ++b)
        acc[a][b] = MFMA16(aF[a], bF[b], acc[a][b]);
  }

  #pragma unroll
  for (int a = 0; a < 2; ++a)
    #pragma unroll
    for (int b = 0; b < 2; ++b)
      #pragma unroll
      for (int rg = 0; rg < 4; ++rg)
        out[(size_t)(m0 + a*16 + lg*4 + rg)*4096 + (n0 + b*16 + lc)] = acc[a][b][rg];
}

extern "C" void kernel_launch(void* const* d_in, const int* in_sizes, int n_in,
                              void* d_out, int out_size, void* d_ws, size_t ws_size,
                              hipStream_t stream) {
  const float* xs    = (const float*)d_in[0];
  const float* xe    = (const float*)d_in[1];
  const float* W1    = (const float*)d_in[2];
  const float* b1    = (const float*)d_in[3];
  const float* W2    = (const float*)d_in[4];
  const float* b2    = (const float*)d_in[5];
  const float* gen   = (const float*)d_in[6];
  const float* scale = (const float*)d_in[7];

  char* ws = (char*)d_ws;
  __bf16* W1b = (__bf16*)ws;                                   // 512 KB
  __bf16* u   = (__bf16*)(ws + 512*1024);                      // 3 MB
  __bf16* Vt  = (__bf16*)(ws + 512*1024 + 3*1024*1024);        // 768 KB

  cvt_w1_kernel<<<1024, 256, 0, stream>>>(W1, W1b);
  build_vt_kernel<<<65, 256, 0, stream>>>(gen, Vt);
  coeff_kernel<<<B_TOT/16, 256, 0, stream>>>(xs, xe, W1b, b1, W2, b2, scale, u);
  out_gemm_kernel<<<(B_TOT/64)*(4096/64), 256, 0, stream>>>(u, Vt, (float*)d_out);
}

// Round 2
// 174.086 us; speedup vs baseline: 1.7059x; 1.7059x over previous
//
#include <hip/hip_runtime.h>

typedef __bf16 bf16x8 __attribute__((ext_vector_type(8)));
typedef __bf16 bf16x4 __attribute__((ext_vector_type(4)));
typedef float f32x4 __attribute__((ext_vector_type(4)));
typedef float f32x2 __attribute__((ext_vector_type(2)));

#define B_TOT   16384
#define DM      512
#define NF      64
#define KU      96   // padded K for final GEMM: 8 G + 64 P + 1 eye + 23 zero

#define MFMA16(a,b,c) __builtin_amdgcn_mfma_f32_16x16x32_bf16(a,b,c,0,0,0)

static __device__ __forceinline__ void gload_lds16(const void* g, void* l) {
  __builtin_amdgcn_global_load_lds((const __attribute__((address_space(1))) char*)g,
                                   (__attribute__((address_space(3))) char*)l, 16, 0, 0);
}

static __device__ __forceinline__ float fast_exp2(float x) {
  return __builtin_amdgcn_exp2f(x);
}
static __device__ __forceinline__ float fast_rcp(float x) {
  return __builtin_amdgcn_rcpf(x);
}

// ---------------- prep: W1->bf16, w2p pack, Vt build ----------------
__global__ __launch_bounds__(256) void prep_kernel(const float* __restrict__ W1,
                                                   const float* __restrict__ W2,
                                                   const float* __restrict__ gen,
                                                   __bf16* __restrict__ W1b,
                                                   __bf16* __restrict__ w2p,
                                                   __bf16* __restrict__ Vt) {
  const int bid = blockIdx.x, tid = threadIdx.x;
  __shared__ float Ga[NF*NF];
  __shared__ float Gb[NF*NF];
  if (bid < 256) {
    const int i = (bid*256 + tid)*4;
    float4 v = *(const float4*)(W1 + i);
    bf16x4 o; o[0]=(__bf16)v.x; o[1]=(__bf16)v.y; o[2]=(__bf16)v.z; o[3]=(__bf16)v.w;
    *(bf16x4*)(W1b + i) = o;
  } else if (bid < 258) {
    const int n = (bid-256)*256 + tid;
    bf16x8 o;
    #pragma unroll
    for (int r = 0; r < 8; ++r) o[r] = (__bf16)W2[r*DM + n];
    *(bf16x8*)(w2p + n*8) = o;
  } else {
    const int vb = bid - 258;
    if (vb < 64) {
      const int r = vb >> 3, s = vb & 7;
      for (int i = tid; i < NF*NF; i += 256) {
        Ga[i] = gen[r*NF*NF + i];
        Gb[i] = gen[s*NF*NF + i];
      }
      __syncthreads();
      const int i  = tid >> 2;
      const int j0 = (tid & 3) * 16;
      float acc[16];
      #pragma unroll
      for (int jj = 0; jj < 16; ++jj) acc[jj] = 0.f;
      for (int k = 0; k < NF; ++k) {
        float a = Ga[i*NF + k];
        #pragma unroll
        for (int jj = 0; jj < 16; ++jj) acc[jj] += a * Gb[k*NF + j0 + jj];
      }
      #pragma unroll
      for (int jj = 0; jj < 16; ++jj)
        Vt[(size_t)(i*NF + j0 + jj)*KU + 8 + vb] = (__bf16)acc[jj];
    } else {
      for (int idx = tid; idx < NF*NF; idx += 256) {
        #pragma unroll
        for (int r = 0; r < 8; ++r) Vt[(size_t)idx*KU + r] = (__bf16)gen[r*NF*NF + idx];
        const int i = idx >> 6, j = idx & 63;
        Vt[(size_t)idx*KU + 72] = (__bf16)((i == j) ? 1.f : 0.f);
        #pragma unroll
        for (int k = 73; k < KU; ++k) Vt[(size_t)idx*KU + k] = (__bf16)0.f;
      }
    }
  }
}

// ---------------- K1a: Gs = xs@W1^T + b1, Ge = xe@W1^T + b1 (bf16 out) ----------------
// grid: bid = nm*128 + mtile ; nm = ntile*2 + mat  (A-sharing WGs land on same XCD mod 8)
// WG: 128x128 tile, 4 waves 2x2 (wave 64x64). BK=32, 16 K-steps, single LDS buf, 2 barriers.
// B-rows permuted: frag nt, lane lc <- row 4*lc+nt  => per-lane 4 consecutive n => 8B stores.
__global__ __launch_bounds__(256, 3) void mlp1_kernel(
    const float* __restrict__ xs, const float* __restrict__ xe,
    const __bf16* __restrict__ W1b, const float* __restrict__ b1,
    __bf16* __restrict__ Gsb, __bf16* __restrict__ Geb) {
  const int bid = blockIdx.x;
  const int mtile = bid & 127;
  const int nm = bid >> 7;
  const int mat = nm & 1;
  const int ntile = nm >> 1;
  const int m0 = mtile*128, n0 = ntile*128;
  const float* __restrict__ X = mat ? xe : xs;
  __bf16* __restrict__ G = mat ? Geb : Gsb;

  __shared__ float As[128*32];    // 16 KB, XOR-swizzled 16B slots (e = row&7)
  __shared__ __bf16 Bs[128*32];   // 8 KB,  XOR-swizzled 16B slots (e = (row>>2)&3)

  const int tid = threadIdx.x;
  const int l = tid & 63, w = tid >> 6;
  const int lc = l & 15, lg = l >> 4;
  const int wm = w >> 1, wn = w & 1;

  auto stage = [&](int k0) {
    #pragma unroll
    for (int call = 0; call < 4; ++call) {
      const int row = call*32 + (tid >> 3);
      const int sp = (tid & 7) ^ (row & 7);
      gload_lds16(X + (size_t)(m0 + row)*DM + k0 + sp*4,
                  (char*)As + call*4096 + tid*16);
    }
    #pragma unroll
    for (int call = 0; call < 2; ++call) {
      const int row = call*64 + (tid >> 2);
      const int sp = (tid & 3) ^ ((row >> 2) & 3);
      gload_lds16(W1b + (size_t)(n0 + row)*DM + k0 + sp*8,
                  (char*)Bs + call*4096 + tid*16);
    }
  };

  f32x4 acc[4][4];
  #pragma unroll
  for (int a = 0; a < 4; ++a)
    #pragma unroll
    for (int b = 0; b < 4; ++b) acc[a][b] = (f32x4)0.f;

  stage(0);
  for (int ks = 0; ks < 16; ++ks) {
    __syncthreads();   // staging visible (drains vmcnt)
    bf16x8 aF[4], bF[4];
    #pragma unroll
    for (int mt = 0; mt < 4; ++mt) {
      const int row = wm*64 + mt*16 + lc;
      const int e = row & 7;
      const float* base = As + row*32;
      f32x4 lo = *(const f32x4*)(base + (((2*lg)   ^ e)*4));
      f32x4 hi = *(const f32x4*)(base + (((2*lg+1) ^ e)*4));
      bf16x8 a;
      a[0]=(__bf16)lo[0]; a[1]=(__bf16)lo[1]; a[2]=(__bf16)lo[2]; a[3]=(__bf16)lo[3];
      a[4]=(__bf16)hi[0]; a[5]=(__bf16)hi[1]; a[6]=(__bf16)hi[2]; a[7]=(__bf16)hi[3];
      aF[mt] = a;
    }
    #pragma unroll
    for (int nt = 0; nt < 4; ++nt) {
      const int row = wn*64 + lc*4 + nt;
      const int sp = lg ^ ((row >> 2) & 3);
      bF[nt] = *(const bf16x8*)(Bs + row*32 + sp*8);
    }
    #pragma unroll
    for (int mt = 0; mt < 4; ++mt)
      #pragma unroll
      for (int nt = 0; nt < 4; ++nt)
        acc[mt][nt] = MFMA16(aF[mt], bF[nt], acc[mt][nt]);
    __syncthreads();   // all reads done before overwrite
    if (ks < 15) stage((ks+1)*32);
  }

  // epilogue: +b1, cvt bf16, packed 8B stores (per-lane n = 4*lc..4*lc+3)
  f32x4 b1v = *(const f32x4*)(b1 + n0 + wn*64 + lc*4);
  #pragma unroll
  for (int mt = 0; mt < 4; ++mt) {
    const int m = m0 + wm*64 + mt*16 + lg*4;
    #pragma unroll
    for (int rg = 0; rg < 4; ++rg) {
      bf16x4 o;
      #pragma unroll
      for (int nt = 0; nt < 4; ++nt) o[nt] = (__bf16)(acc[mt][nt][rg] + b1v[nt]);
      *(bf16x4*)(G + (size_t)(m + rg)*DM + n0 + wn*64 + lc*4) = o;
    }
  }
}

// ---------------- K1b: coefficients ----------------
// per wave: 4 rows; lane = row_in_wave*16 + slice; slice covers n = {c*128 + slice*8 + i}
__global__ __launch_bounds__(256, 4) void coeff2_kernel(
    const __bf16* __restrict__ Gsb, const __bf16* __restrict__ Geb,
    const __bf16* __restrict__ w2p, const float* __restrict__ b2,
    const float* __restrict__ scale_p, __bf16* __restrict__ u) {
  const int tid = threadIdx.x;
  const int wv = tid >> 6, l = tid & 63;
  const int s = l & 15;
  const int row = blockIdx.x*16 + wv*4 + (l >> 4);
  const size_t rb = (size_t)row * DM;

  float pz[4][8];
  #pragma unroll
  for (int st = 0; st < 4; ++st)
    #pragma unroll
    for (int r = 0; r < 8; ++r) pz[st][r] = 0.f;

  #pragma unroll
  for (int c = 0; c < 4; ++c) {
    const int nb = c*128 + s*8;
    bf16x8 s8 = *(const bf16x8*)(Gsb + rb + nb);
    bf16x8 e8 = *(const bf16x8*)(Geb + rb + nb);
    #pragma unroll
    for (int i = 0; i < 8; ++i) {
      const float sv = (float)s8[i];
      const float dv = (float)e8[i] - sv;
      bf16x8 wv8 = *(const bf16x8*)(w2p + (size_t)(nb + i)*8);
      float w2f[8];
      #pragma unroll
      for (int r = 0; r < 8; ++r) w2f[r] = (float)wv8[r];
      #pragma unroll
      for (int st = 0; st < 4; ++st) {
        const float t = 0.125f + 0.25f*(float)st;
        const float mid = fmaf(t, dv, sv);
        // gelu ~= x * sigmoid(1.702 x); sigmoid via exp2 (hw v_exp_f32)
        const float g = mid * fast_rcp(1.f + fast_exp2(-2.4554669f * mid));
        #pragma unroll
        for (int r = 0; r < 8; ++r) pz[st][r] = fmaf(g, w2f[r], pz[st][r]);
      }
    }
  }

  // reduce over the 16 slices of this row
  #pragma unroll
  for (int st = 0; st < 4; ++st)
    #pragma unroll
    for (int r = 0; r < 8; ++r) {
      float v = pz[st][r];
      v += __shfl_xor(v, 1); v += __shfl_xor(v, 2);
      v += __shfl_xor(v, 4); v += __shfl_xor(v, 8);
      pz[st][r] = v;
    }

  // each lane finalizes r = s&7, then gathers all 8
  const int r = s & 7;
  const float b2r = b2[r];
  float sum = 0.f;
  #pragma unroll
  for (int st = 0; st < 4; ++st) {
    const float z = pz[st][r] + b2r;
    const float te = fast_exp2(2.8853901f * z);   // e^(2z); inf-safe: tanh->1
    sum += 1.f - 2.f * fast_rcp(te + 1.f);
  }
  const float cs_own = sum * 0.25f * (*scale_p);  // * dt * scale
  float cs[8];
  #pragma unroll
  for (int k = 0; k < 8; ++k) cs[k] = __shfl(cs_own, (l & 48) | k);

  // write u[row][96]: slice s writes k in [6s, 6s+6)
  __bf16* up = u + (size_t)row*KU;
  #pragma unroll
  for (int j = 0; j < 6; ++j) {
    const int k = s*6 + j;
    float val;
    if (k < 8)        val = cs[k];
    else if (k < 72)  { const int rs = k - 8; val = 0.5f*cs[rs>>3]*cs[rs&7]; }
    else if (k == 72) val = 1.f;
    else              val = 0.f;
    up[k] = (__bf16)val;
  }
}

// ---------------- K3: out[b][ij] = sum_k u[b][k] * Vt[ij][k] ----------------
// B-rows permuted: frag b, lane lc <- row 2*lc+b  => per-lane f32x2 coalesced stores.
__global__ __launch_bounds__(256) void out_gemm_kernel(
    const __bf16* __restrict__ u, const __bf16* __restrict__ Vt,
    float* __restrict__ out) {
  const int bid = blockIdx.x;
  const int mb = bid & 255, nb = bid >> 8;   // n-major grid: u m-tile stays on one XCD
  const int tid = threadIdx.x;
  const int l = tid & 63, w = tid >> 6;
  const int lc = l & 15, lg = l >> 4;
  const int mw = w >> 1, nw = w & 1;
  const int m0 = mb*64 + mw*32;
  const int n0 = nb*64 + nw*32;

  f32x4 acc[2][2];
  #pragma unroll
  for (int a = 0; a < 2; ++a)
    #pragma unroll
    for (int b = 0; b < 2; ++b) acc[a][b] = (f32x4)0.f;

  #pragma unroll
  for (int ks = 0; ks < 3; ++ks) {
    const int k0 = ks*32 + lg*8;
    bf16x8 aF[2], bF[2];
    #pragma unroll
    for (int a = 0; a < 2; ++a)
      aF[a] = *(const bf16x8*)(u + (size_t)(m0 + a*16 + lc)*KU + k0);
    #pragma unroll
    for (int b = 0; b < 2; ++b)
      bF[b] = *(const bf16x8*)(Vt + (size_t)(n0 + lc*2 + b)*KU + k0);
    #pragma unroll
    for (int a = 0; a < 2; ++a)
      #pragma unroll
      for (int b = 0; b < 2; ++b)
        acc[a][b] = MFMA16(aF[a], bF[b], acc[a][b]);
  }

  #pragma unroll
  for (int a = 0; a < 2; ++a)
    #pragma unroll
    for (int rg = 0; rg < 4; ++rg) {
      f32x2 o; o[0] = acc[a][0][rg]; o[1] = acc[a][1][rg];
      *(f32x2*)(out + (size_t)(m0 + a*16 + lg*4 + rg)*4096 + n0 + lc*2) = o;
    }
}

extern "C" void kernel_launch(void* const* d_in, const int* in_sizes, int n_in,
                              void* d_out, int out_size, void* d_ws, size_t ws_size,
                              hipStream_t stream) {
  const float* xs    = (const float*)d_in[0];
  const float* xe    = (const float*)d_in[1];
  const float* W1    = (const float*)d_in[2];
  const float* b1    = (const float*)d_in[3];
  const float* W2    = (const float*)d_in[4];
  const float* b2    = (const float*)d_in[5];
  const float* gen   = (const float*)d_in[6];
  const float* scale = (const float*)d_in[7];

  char* ws = (char*)d_ws;
  __bf16* W1b = (__bf16*)ws;                                    // 512 KB
  __bf16* u   = (__bf16*)(ws + 512*1024);                       // 3 MB
  __bf16* Vt  = (__bf16*)(ws + 512*1024 + 3*1024*1024);         // 768 KB
  __bf16* w2p = (__bf16*)(ws + 512*1024 + 3*1024*1024 + 768*1024); // 8 KB

  // Gs/Ge scratch lives in d_out (32 MB of 256 MB), fully overwritten by K3.
  __bf16* Gsb = (__bf16*)d_out;
  __bf16* Geb = (__bf16*)d_out + (size_t)B_TOT*DM;

  prep_kernel<<<323, 256, 0, stream>>>(W1, W2, gen, W1b, w2p, Vt);
  mlp1_kernel<<<1024, 256, 0, stream>>>(xs, xe, W1b, b1, Gsb, Geb);
  coeff2_kernel<<<B_TOT/16, 256, 0, stream>>>(Gsb, Geb, w2p, b2, scale, u);
  out_gemm_kernel<<<256*64, 256, 0, stream>>>(u, Vt, (float*)d_out);
}

// Round 3
// 146.500 us; speedup vs baseline: 2.0271x; 1.1883x over previous
//
#include <hip/hip_runtime.h>

typedef __bf16 bf16x8 __attribute__((ext_vector_type(8)));
typedef __bf16 bf16x4 __attribute__((ext_vector_type(4)));
typedef float f32x4 __attribute__((ext_vector_type(4)));

#define B_TOT   16384
#define DM      512
#define NF      64
#define KU      64   // K for final GEMM: 8 G + 36 sym pairs + 1 eye + 19 zero

#define MFMA16(a,b,c) __builtin_amdgcn_mfma_f32_16x16x32_bf16(a,b,c,0,0,0)

static __device__ __forceinline__ void gload_lds16(const void* g, void* l) {
  __builtin_amdgcn_global_load_lds((const __attribute__((address_space(1))) char*)g,
                                   (__attribute__((address_space(3))) char*)l, 16, 0, 0);
}

static __device__ __forceinline__ float fast_exp2(float x) {
  return __builtin_amdgcn_exp2f(x);
}
static __device__ __forceinline__ float fast_rcp(float x) {
  return __builtin_amdgcn_rcpf(x);
}

// ---------------- prep: W1->bf16, w2p pack, Vt build ----------------
// grid 298: [0,256) W1 cvt; [256,258) w2p; [258,294) pair-product cols; [294,298) static cols
__global__ __launch_bounds__(256) void prep_kernel(const float* __restrict__ W1,
                                                   const float* __restrict__ W2,
                                                   const float* __restrict__ gen,
                                                   __bf16* __restrict__ W1b,
                                                   __bf16* __restrict__ w2p,
                                                   __bf16* __restrict__ Vt) {
  const int bid = blockIdx.x, tid = threadIdx.x;
  __shared__ float Ga[NF*NF];
  __shared__ float Gb[NF*NF];
  if (bid < 256) {
    const int i = (bid*256 + tid)*4;
    float4 v = *(const float4*)(W1 + i);
    bf16x4 o; o[0]=(__bf16)v.x; o[1]=(__bf16)v.y; o[2]=(__bf16)v.z; o[3]=(__bf16)v.w;
    *(bf16x4*)(W1b + i) = o;
  } else if (bid < 258) {
    const int n = (bid-256)*256 + tid;
    bf16x8 o;
    #pragma unroll
    for (int r = 0; r < 8; ++r) o[r] = (__bf16)W2[r*DM + n];
    *(bf16x8*)(w2p + n*8) = o;
  } else if (bid < 294) {
    // pair p -> (r,s), r<=s: col 8+p = G_r G_s + (r!=s) G_s G_r
    const int p = bid - 258;
    int r = (p>=8)+(p>=15)+(p>=21)+(p>=26)+(p>=30)+(p>=33)+(p>=35);
    const int baser = r*8 - ((r*(r-1))>>1);
    const int s = r + p - baser;
    for (int i = tid; i < NF*NF; i += 256) {
      Ga[i] = gen[r*NF*NF + i];
      Gb[i] = gen[s*NF*NF + i];
    }
    __syncthreads();
    const int i  = tid >> 2;
    const int j0 = (tid & 3) * 16;
    float acc[16];
    #pragma unroll
    for (int jj = 0; jj < 16; ++jj) acc[jj] = 0.f;
    for (int k = 0; k < NF; ++k) {
      float a = Ga[i*NF + k];
      #pragma unroll
      for (int jj = 0; jj < 16; ++jj) acc[jj] += a * Gb[k*NF + j0 + jj];
    }
    if (r != s) {
      for (int k = 0; k < NF; ++k) {
        float a = Gb[i*NF + k];
        #pragma unroll
        for (int jj = 0; jj < 16; ++jj) acc[jj] += a * Ga[k*NF + j0 + jj];
      }
    }
    #pragma unroll
    for (int jj = 0; jj < 16; ++jj)
      Vt[(size_t)(i*NF + j0 + jj)*KU + 8 + p] = (__bf16)acc[jj];
  } else {
    // static cols: 0..7 = G_r[ij]; 44 = eye; 45..63 = 0
    const int q = bid - 294;
    #pragma unroll
    for (int v = 0; v < 4; ++v) {
      const int ij = q*1024 + tid*4 + v;
      bf16x8 g8;
      #pragma unroll
      for (int r = 0; r < 8; ++r) g8[r] = (__bf16)gen[r*NF*NF + ij];
      __bf16* row = Vt + (size_t)ij*KU;
      *(bf16x8*)row = g8;
      const float eye = ((ij >> 6) == (ij & 63)) ? 1.f : 0.f;
      bf16x4 e4; e4[0] = (__bf16)eye; e4[1] = (__bf16)0.f; e4[2] = (__bf16)0.f; e4[3] = (__bf16)0.f;
      *(bf16x4*)(row + 44) = e4;
      bf16x8 z8;
      #pragma unroll
      for (int k = 0; k < 8; ++k) z8[k] = (__bf16)0.f;
      *(bf16x8*)(row + 48) = z8;
      *(bf16x8*)(row + 56) = z8;
    }
  }
}

// ---------------- K1a: Gs = xs@W1^T + b1, Ge = xe@W1^T + b1 (bf16 out) ----------------
// 128x128 tile, BK=64, 8 K-steps, single LDS buffer (48 KB), 3 blocks/CU.
// B-rows permuted: frag nt, lane lc <- row 4*lc+nt  => per-lane 4 consecutive n => 8B stores.
__global__ __launch_bounds__(256, 3) void mlp1_kernel(
    const float* __restrict__ xs, const float* __restrict__ xe,
    const __bf16* __restrict__ W1b, const float* __restrict__ b1,
    __bf16* __restrict__ Gsb, __bf16* __restrict__ Geb) {
  const int bid = blockIdx.x;
  const int mtile = bid & 127;
  const int nm = bid >> 7;
  const int mat = nm & 1;
  const int ntile = nm >> 1;
  const int m0 = mtile*128, n0 = ntile*128;
  const float* __restrict__ X = mat ? xe : xs;
  __bf16* __restrict__ G = mat ? Geb : Gsb;

  __shared__ float As[128*64];    // 32 KB; row = 16 slots of 16B, slot' = slot ^ (row&7)
  __shared__ __bf16 Bs[128*64];   // 16 KB; row = 8 slots of 16B, slot' = slot ^ ((row>>2)&7)

  const int tid = threadIdx.x;
  const int l = tid & 63, w = tid >> 6;
  const int lc = l & 15, lg = l >> 4;
  const int wm = w >> 1, wn = w & 1;

  auto stage = [&](int k0) {
    #pragma unroll
    for (int c = 0; c < 8; ++c) {
      const int row = c*16 + (tid >> 4);
      const int sp = (tid & 15) ^ (row & 7);
      gload_lds16(X + (size_t)(m0 + row)*DM + k0 + sp*4,
                  (char*)As + c*4096 + tid*16);
    }
    #pragma unroll
    for (int c = 0; c < 4; ++c) {
      const int row = c*32 + (tid >> 3);
      const int sp = (tid & 7) ^ ((row >> 2) & 7);
      gload_lds16(W1b + (size_t)(n0 + row)*DM + k0 + sp*8,
                  (char*)Bs + c*4096 + tid*16);
    }
  };

  f32x4 acc[4][4];
  #pragma unroll
  for (int a = 0; a < 4; ++a)
    #pragma unroll
    for (int b = 0; b < 4; ++b) acc[a][b] = (f32x4)0.f;

  stage(0);
  for (int ks = 0; ks < 8; ++ks) {
    __syncthreads();   // staging visible (drains vmcnt)
    #pragma unroll
    for (int kk = 0; kk < 2; ++kk) {
      bf16x8 aF[4], bF[4];
      #pragma unroll
      for (int mt = 0; mt < 4; ++mt) {
        const int row = wm*64 + mt*16 + lc;
        const int e = row & 7;
        const int s0 = kk*8 + 2*lg;
        const float* base = As + row*64;
        f32x4 lo = *(const f32x4*)(base + ((s0     ^ e)*4));
        f32x4 hi = *(const f32x4*)(base + (((s0+1) ^ e)*4));
        bf16x8 a;
        a[0]=(__bf16)lo[0]; a[1]=(__bf16)lo[1]; a[2]=(__bf16)lo[2]; a[3]=(__bf16)lo[3];
        a[4]=(__bf16)hi[0]; a[5]=(__bf16)hi[1]; a[6]=(__bf16)hi[2]; a[7]=(__bf16)hi[3];
        aF[mt] = a;
      }
      #pragma unroll
      for (int nt = 0; nt < 4; ++nt) {
        const int row = wn*64 + lc*4 + nt;
        const int sp = (kk*4 + lg) ^ ((row >> 2) & 7);
        bF[nt] = *(const bf16x8*)(Bs + row*64 + sp*8);
      }
      #pragma unroll
      for (int mt = 0; mt < 4; ++mt)
        #pragma unroll
        for (int nt = 0; nt < 4; ++nt)
          acc[mt][nt] = MFMA16(aF[mt], bF[nt], acc[mt][nt]);
    }
    __syncthreads();   // all reads done before overwrite
    if (ks < 7) stage((ks+1)*64);
  }

  // epilogue: +b1, cvt bf16, packed 8B stores (per-lane n = 4*lc..4*lc+3)
  f32x4 b1v = *(const f32x4*)(b1 + n0 + wn*64 + lc*4);
  #pragma unroll
  for (int mt = 0; mt < 4; ++mt) {
    const int m = m0 + wm*64 + mt*16 + lg*4;
    #pragma unroll
    for (int rg = 0; rg < 4; ++rg) {
      bf16x4 o;
      #pragma unroll
      for (int nt = 0; nt < 4; ++nt) o[nt] = (__bf16)(acc[mt][nt][rg] + b1v[nt]);
      *(bf16x4*)(G + (size_t)(m + rg)*DM + n0 + wn*64 + lc*4) = o;
    }
  }
}

// ---------------- K1b: coefficients ----------------
// per wave: 4 rows; lane = row_in_wave*16 + slice; slice covers n = {c*128 + slice*8 + i}
__global__ __launch_bounds__(256, 4) void coeff2_kernel(
    const __bf16* __restrict__ Gsb, const __bf16* __restrict__ Geb,
    const __bf16* __restrict__ w2p, const float* __restrict__ b2,
    const float* __restrict__ scale_p, __bf16* __restrict__ u) {
  const int tid = threadIdx.x;
  const int wv = tid >> 6, l = tid & 63;
  const int ls = l & 15;
  const int row = blockIdx.x*16 + wv*4 + (l >> 4);
  const size_t rb = (size_t)row * DM;

  float pz[4][8];
  #pragma unroll
  for (int st = 0; st < 4; ++st)
    #pragma unroll
    for (int r = 0; r < 8; ++r) pz[st][r] = 0.f;

  #pragma unroll
  for (int c = 0; c < 4; ++c) {
    const int nb = c*128 + ls*8;
    bf16x8 s8 = *(const bf16x8*)(Gsb + rb + nb);
    bf16x8 e8 = *(const bf16x8*)(Geb + rb + nb);
    #pragma unroll
    for (int i = 0; i < 8; ++i) {
      const float sv = (float)s8[i];
      const float dv = (float)e8[i] - sv;
      bf16x8 wv8 = *(const bf16x8*)(w2p + (size_t)(nb + i)*8);
      float w2f[8];
      #pragma unroll
      for (int r = 0; r < 8; ++r) w2f[r] = (float)wv8[r];
      #pragma unroll
      for (int st = 0; st < 4; ++st) {
        const float t = 0.125f + 0.25f*(float)st;
        const float mid = fmaf(t, dv, sv);
        // gelu ~= x * sigmoid(1.702 x); sigmoid via exp2 (hw v_exp_f32)
        const float g = mid * fast_rcp(1.f + fast_exp2(-2.4554669f * mid));
        #pragma unroll
        for (int r = 0; r < 8; ++r) pz[st][r] = fmaf(g, w2f[r], pz[st][r]);
      }
    }
  }

  // reduce over the 16 slices of this row
  #pragma unroll
  for (int st = 0; st < 4; ++st)
    #pragma unroll
    for (int r = 0; r < 8; ++r) {
      float v = pz[st][r];
      v += __shfl_xor(v, 1); v += __shfl_xor(v, 2);
      v += __shfl_xor(v, 4); v += __shfl_xor(v, 8);
      pz[st][r] = v;
    }

  // each lane finalizes r = ls&7, then values are gathered by shfl
  const int rown = ls & 7;
  const float b2r = b2[rown];
  float sum = 0.f;
  #pragma unroll
  for (int st = 0; st < 4; ++st) {
    const float z = pz[st][rown] + b2r;
    const float te = fast_exp2(2.8853901f * z);   // e^(2z); inf-safe: tanh->1
    sum += 1.f - 2.f * fast_rcp(te + 1.f);
  }
  const float cs_own = sum * 0.25f * (*scale_p);  // * dt * scale

  // write u[row][64]: slice ls writes cols 4ls..4ls+3 as one 8B store
  bf16x4 o;
  #pragma unroll
  for (int j = 0; j < 4; ++j) {
    const int k = ls*4 + j;
    float val;
    if (k < 8) {
      val = __shfl(cs_own, (l & 48) | k);
    } else if (k < 44) {
      const int p = k - 8;
      int r = (p>=8)+(p>=15)+(p>=21)+(p>=26)+(p>=30)+(p>=33)+(p>=35);
      const int baser = r*8 - ((r*(r-1))>>1);
      const int s2 = r + p - baser;
      const float cr  = __shfl(cs_own, (l & 48) | r);
      const float cs2 = __shfl(cs_own, (l & 48) | s2);
      val = 0.5f * cr * cs2;
    } else if (k == 44) {
      val = 1.f;
    } else {
      val = 0.f;
    }
    o[j] = (__bf16)val;
  }
  *(bf16x4*)(u + (size_t)row*KU + ls*4) = o;
}

// ---------------- K3: out[b][ij] = sum_k u[b][k] * Vt[ij][k]  (K=64) ----------------
// m-major grid; WG tile 64 rows x 256 cols, 4 waves side-by-side (each 64x64).
// B-rows permuted: frag b, lane lc <- col lc*4+b  => per-lane f32x4 stores, 1KB/row/WG.
__global__ __launch_bounds__(256) void out_gemm_kernel(
    const __bf16* __restrict__ u, const __bf16* __restrict__ Vt,
    float* __restrict__ out) {
  const int bid = blockIdx.x;
  const int mb = bid >> 4, nbq = bid & 15;
  const int tid = threadIdx.x;
  const int l = tid & 63, wv = tid >> 6;
  const int lc = l & 15, lg = l >> 4;
  const int m0 = mb*64;
  const int n0 = nbq*256 + wv*64;

  f32x4 acc[4][4];
  #pragma unroll
  for (int a = 0; a < 4; ++a)
    #pragma unroll
    for (int b = 0; b < 4; ++b) acc[a][b] = (f32x4)0.f;

  #pragma unroll
  for (int ks = 0; ks < 2; ++ks) {
    const int k0 = ks*32 + lg*8;
    bf16x8 aF[4], bF[4];
    #pragma unroll
    for (int a = 0; a < 4; ++a)
      aF[a] = *(const bf16x8*)(u + (size_t)(m0 + a*16 + lc)*KU + k0);
    #pragma unroll
    for (int b = 0; b < 4; ++b)
      bF[b] = *(const bf16x8*)(Vt + (size_t)(n0 + lc*4 + b)*KU + k0);
    #pragma unroll
    for (int a = 0; a < 4; ++a)
      #pragma unroll
      for (int b = 0; b < 4; ++b)
        acc[a][b] = MFMA16(aF[a], bF[b], acc[a][b]);
  }

  #pragma unroll
  for (int a = 0; a < 4; ++a)
    #pragma unroll
    for (int rg = 0; rg < 4; ++rg) {
      f32x4 o; o[0] = acc[a][0][rg]; o[1] = acc[a][1][rg];
      o[2] = acc[a][2][rg]; o[3] = acc[a][3][rg];
      *(f32x4*)(out + (size_t)(m0 + a*16 + lg*4 + rg)*4096 + n0 + lc*4) = o;
    }
}

extern "C" void kernel_launch(void* const* d_in, const int* in_sizes, int n_in,
                              void* d_out, int out_size, void* d_ws, size_t ws_size,
                              hipStream_t stream) {
  const float* xs    = (const float*)d_in[0];
  const float* xe    = (const float*)d_in[1];
  const float* W1    = (const float*)d_in[2];
  const float* b1    = (const float*)d_in[3];
  const float* W2    = (const float*)d_in[4];
  const float* b2    = (const float*)d_in[5];
  const float* gen   = (const float*)d_in[6];
  const float* scale = (const float*)d_in[7];

  char* ws = (char*)d_ws;
  __bf16* W1b = (__bf16*)ws;                                    // 512 KB
  __bf16* u   = (__bf16*)(ws + 512*1024);                       // 2 MB
  __bf16* Vt  = (__bf16*)(ws + 512*1024 + 2*1024*1024);         // 512 KB
  __bf16* w2p = (__bf16*)(ws + 512*1024 + 2*1024*1024 + 512*1024); // 8 KB

  // Gs/Ge scratch lives in d_out (32 MB of 256 MB), fully overwritten by K3.
  __bf16* Gsb = (__bf16*)d_out;
  __bf16* Geb = (__bf16*)d_out + (size_t)B_TOT*DM;

  prep_kernel<<<298, 256, 0, stream>>>(W1, W2, gen, W1b, w2p, Vt);
  mlp1_kernel<<<1024, 256, 0, stream>>>(xs, xe, W1b, b1, Gsb, Geb);
  coeff2_kernel<<<B_TOT/16, 256, 0, stream>>>(Gsb, Geb, w2p, b2, scale, u);
  out_gemm_kernel<<<256*16, 256, 0, stream>>>(u, Vt, (float*)d_out);
}